// Round 4
// baseline (20121.068 us; speedup 1.0000x reference)
//
#include <hip/hip_runtime.h>

typedef unsigned short u16;
typedef unsigned int u32;
typedef __bf16 bf16x8 __attribute__((ext_vector_type(8)));
typedef float f32x4 __attribute__((ext_vector_type(4)));
typedef u16 u16x8 __attribute__((ext_vector_type(8)));

#define AS1 __attribute__((address_space(1)))
#define AS3 __attribute__((address_space(3)))

constexpr int Bsz = 512;   // batch
constexpr int LATn = 128;  // latent
constexpr int Hn  = 1024;  // hidden
constexpr int G4H = 4096;  // 4*H
constexpr int NBLK = 256;

__device__ __forceinline__ u16 f2bf(float x){
  u32 u = __float_as_uint(x);
  return (u16)((u + 0x7FFFu + ((u >> 16) & 1u)) >> 16);
}
__device__ __forceinline__ float bf2f(u16 h){ return __uint_as_float(((u32)h) << 16); }

__device__ __forceinline__ float sigm(float x){
  float e = __builtin_amdgcn_exp2f(x * -1.44269504088896f);
  return __builtin_amdgcn_rcpf(1.0f + e);
}
__device__ __forceinline__ float tanh_f(float x){
  float e = __builtin_amdgcn_exp2f(x * -2.88539008177793f);
  return __builtin_amdgcn_rcpf(1.0f + e) * 2.0f - 1.0f;
}

__device__ __forceinline__ bf16x8 ld8(const u16* p){
  u16x8 v = *reinterpret_cast<const u16x8*>(p);
  return __builtin_bit_cast(bf16x8, v);
}

__device__ __forceinline__ void load16_lds(const u16* g, u16* l){
  __builtin_amdgcn_global_load_lds((AS1 void*)(u16*)g, (AS3 void*)l, 16, 0, 0);
}

// ---------------- repack: fp32 -> bf16 hi/lo, gate-interleaved weight layout ----------------
// W_hh src row = g*1024 + jj  (gate-major packed col: drow = (jj>>4)*64 + g*16 + (jj&15))
__global__ void repack_kernel(
    const float* __restrict__ Whh, const float* __restrict__ b_ih, const float* __restrict__ b_hh,
    const float* __restrict__ Wih, const float* __restrict__ z,
    const float* __restrict__ Wzh, const float* __restrict__ Wzc,
    u16* wp_hi, u16* wp_lo, u16* zp_hi, u16* zp_lo,
    u16* wzh_hi, u16* wzh_lo, u16* wzc_hi, u16* wzc_lo,
    float* bpack, float* wihpack, u32* cnt)
{
  const int idx0 = blockIdx.x * blockDim.x + threadIdx.x;
  const int stride = gridDim.x * blockDim.x;
  if (idx0 < 4) cnt[idx0] = 0u;   // group-barrier counters: zero every launch
  for (int i = idx0; i < G4H * Hn; i += stride){
    int row = i >> 10, k = i & 1023;
    int g = row >> 10, jj = row & 1023;
    int drow = (jj >> 4) * 64 + g * 16 + (jj & 15);
    float x = Whh[i];
    u16 hi = f2bf(x);
    wp_hi[drow * 1024 + k] = hi;
    wp_lo[drow * 1024 + k] = f2bf(x - bf2f(hi));
  }
  for (int i = idx0; i < Bsz * LATn; i += stride){
    float x = z[i]; u16 hi = f2bf(x);
    zp_hi[i] = hi; zp_lo[i] = f2bf(x - bf2f(hi));
  }
  for (int i = idx0; i < Hn * LATn; i += stride){
    float x = Wzh[i]; u16 h1 = f2bf(x); wzh_hi[i] = h1; wzh_lo[i] = f2bf(x - bf2f(h1));
    float y = Wzc[i]; u16 h2 = f2bf(y); wzc_hi[i] = h2; wzc_lo[i] = f2bf(y - bf2f(h2));
  }
  for (int i = idx0; i < G4H; i += stride){
    int g = i >> 10, jj = i & 1023;
    int drow = (jj >> 4) * 64 + g * 16 + (jj & 15);
    bpack[drow] = b_ih[i] + b_hh[i];
    wihpack[drow] = Wih[i];
  }
}

// ---------------- persistent LSTM kernel ----------------
// 256 blocks x 512 threads (8 waves = 4 bgroups x 32 rows  X  2 k-halves).
// Block (bt,jt): bt = (bid&7)>>1, jt = (bid>>3)*2+(bid&1).
// Whi LDS-resident; Wlo + h from global with depth-3 register prefetch ring.
// Coherence protocol identical to the passing V4 (agent fences + atomic counter barrier).
__global__ __launch_bounds__(512, 1) void lstm_persist(
    const u16* __restrict__ wp_hi, const u16* __restrict__ wp_lo,
    const float* __restrict__ bpack, const float* __restrict__ wihpack,
    const float* __restrict__ Wout, const float* __restrict__ bout,
    const u16* __restrict__ zp_hi, const u16* __restrict__ zp_lo,
    const u16* __restrict__ wzh_hi, const u16* __restrict__ wzh_lo,
    const u16* __restrict__ wzc_hi, const u16* __restrict__ wzc_lo,
    const float* __restrict__ bzh, const float* __restrict__ bzc,
    u16* hb_hi, u16* hb_lo,      // [2][512][1024] bf16 hi/lo, double-buffered
    float* ypart,                 // [2][4bt][128][64jt] (transposed for coalesced reads)
    float* outp, const int* tlen, u32* cnt)
{
  __shared__ __align__(16) u16 ldsW[16 * 4096];  // 128 KiB: [c64][col][slot^swz][8]
  __shared__ float exch[4096];                   // 16 KiB k-partial exchange (2 phases)
  __shared__ float x_lds[128];

  const int tid = threadIdx.x;
  const int lane = tid & 63, w = tid >> 6;
  const int r = lane & 15, q = lane >> 4;
  const int kg = w & 1, bgroup = w >> 1;        // 2 k-halves x 4 batch-groups of 32 rows
  const int bid = blockIdx.x;
  const int bt = (bid & 7) >> 1;
  const int jt = ((bid >> 3) << 1) | (bid & 1);
  const int j = jt * 16 + r;
  const int T = tlen[0];

  // ---- stage Whi into LDS (once): 16 slabs x 512 chunks, one chunk per thread ----
  #pragma unroll 4
  for (int c64 = 0; c64 < 16; ++c64){
    int scol = tid >> 3, sp = tid & 7;
    int s = sp ^ (scol & 7);                        // inverse of read-side swizzle
    load16_lds(wp_hi + (size_t)(jt * 64 + scol) * 1024 + c64 * 64 + s * 8,
               &ldsW[c64 * 4096 + w * 512]);        // wave-uniform dst + lane*16B
  }

  // per-lane constants
  float bias_r[4], wih_r[4];
  #pragma unroll
  for (int nt = 0; nt < 4; ++nt){
    bias_r[nt] = bpack[jt * 64 + nt * 16 + r];
    wih_r[nt]  = wihpack[jt * 64 + nt * 16 + r];
  }
  const float wout_r = Wout[j];
  const float bo = bout[0];

  // ---- init: h0 = tanh(z Wzh^T + bzh), c0 = tanh(z Wzc^T + bzc) (kg==0 waves) ----
  float creg[8];
  if (kg == 0){
    const float bh0 = bzh[j], bc0 = bzc[j];
    f32x4 acc_h[2], acc_c[2];
    #pragma unroll
    for (int mt = 0; mt < 2; ++mt){
      acc_h[mt] = f32x4{bh0, bh0, bh0, bh0};
      acc_c[mt] = f32x4{bc0, bc0, bc0, bc0};
    }
    #pragma unroll
    for (int ks = 0; ks < 4; ++ks){
      const int ak = ks * 32 + q * 8;
      bf16x8 bhh = ld8(wzh_hi + j * LATn + ak);
      bf16x8 bhl = ld8(wzh_lo + j * LATn + ak);
      bf16x8 bch = ld8(wzc_hi + j * LATn + ak);
      bf16x8 bcl = ld8(wzc_lo + j * LATn + ak);
      #pragma unroll
      for (int mt = 0; mt < 2; ++mt){
        const int arow = bt * 128 + bgroup * 32 + mt * 16 + r;
        bf16x8 ah = ld8(zp_hi + arow * LATn + ak);
        bf16x8 al = ld8(zp_lo + arow * LATn + ak);
        acc_h[mt] = __builtin_amdgcn_mfma_f32_16x16x32_bf16(ah, bhh, acc_h[mt], 0, 0, 0);
        acc_h[mt] = __builtin_amdgcn_mfma_f32_16x16x32_bf16(ah, bhl, acc_h[mt], 0, 0, 0);
        acc_h[mt] = __builtin_amdgcn_mfma_f32_16x16x32_bf16(al, bhh, acc_h[mt], 0, 0, 0);
        acc_c[mt] = __builtin_amdgcn_mfma_f32_16x16x32_bf16(ah, bch, acc_c[mt], 0, 0, 0);
        acc_c[mt] = __builtin_amdgcn_mfma_f32_16x16x32_bf16(ah, bcl, acc_c[mt], 0, 0, 0);
        acc_c[mt] = __builtin_amdgcn_mfma_f32_16x16x32_bf16(al, bch, acc_c[mt], 0, 0, 0);
      }
    }
    #pragma unroll
    for (int mt = 0; mt < 2; ++mt)
      #pragma unroll
      for (int e = 0; e < 4; ++e){
        const int idx = mt * 4 + e;
        creg[idx] = tanh_f(acc_c[mt][e]);
        float h0 = tanh_f(acc_h[mt][e]);
        const int row = bt * 128 + bgroup * 32 + mt * 16 + q * 4 + e;
        u16 hi = f2bf(h0);
        hb_hi[row * Hn + j] = hi;
        hb_lo[row * Hn + j] = f2bf(h0 - bf2f(hi));
      }
  }
  if (tid < 128) x_lds[tid] = 0.0f;
  __syncthreads();

  // ---- group barrier (64 blocks sharing bt), hand-rolled; capped spin as hang hedge ----
  __builtin_amdgcn_fence(__ATOMIC_RELEASE, "agent");
  __syncthreads();
  if (tid == 0){
    __hip_atomic_fetch_add(cnt + bt, 1u, __ATOMIC_RELAXED, __HIP_MEMORY_SCOPE_AGENT);
    for (int spin = 0; spin < (1 << 18); ++spin){
      if (__hip_atomic_load(cnt + bt, __ATOMIC_RELAXED, __HIP_MEMORY_SCOPE_AGENT) >= 64u) break;
      __builtin_amdgcn_s_sleep(2);
    }
  }
  __syncthreads();
  __builtin_amdgcn_fence(__ATOMIC_ACQUIRE, "agent");

  // ---- time loop ----
  #pragma unroll 1
  for (int t = 0; t < T; ++t){
    const int pb = t & 1;
    const u16* hs_hi = hb_hi + pb * (Bsz * Hn);
    const u16* hs_lo = hb_lo + pb * (Bsz * Hn);
    u16* hd_hi = hb_hi + (pb ^ 1) * (Bsz * Hn);
    u16* hd_lo = hb_lo + (pb ^ 1) * (Bsz * Hn);

    f32x4 acc[2][4];
    if (kg == 0){
      #pragma unroll
      for (int mt = 0; mt < 2; ++mt)
        #pragma unroll
        for (int e = 0; e < 4; ++e){
          const float xv = x_lds[bgroup * 32 + mt * 16 + q * 4 + e];
          #pragma unroll
          for (int nt = 0; nt < 4; ++nt)
            acc[mt][nt][e] = bias_r[nt] + xv * wih_r[nt];
        }
    } else {
      #pragma unroll
      for (int mt = 0; mt < 2; ++mt)
        #pragma unroll
        for (int nt = 0; nt < 4; ++nt)
          acc[mt][nt] = f32x4{0.f, 0.f, 0.f, 0.f};
    }

    const u16* ha_hi = hs_hi + (bt * 128 + bgroup * 32 + r) * Hn + kg * 512 + q * 8;
    const u16* ha_lo = hs_lo + (bt * 128 + bgroup * 32 + r) * Hn + kg * 512 + q * 8;
    const u16* wl    = wp_lo + (size_t)(jt * 64 + r) * 1024 + kg * 512 + q * 8;

    // ---- depth-3 prefetch ring over the 16 k-chunks of this wave's half ----
    bf16x8 rahi[3][2], ralo[3][2], rblo[3][4];
    #define LOADIT(cc, ss) { \
      const int ko_ = (cc) * 32; \
      rahi[ss][0] = ld8(ha_hi + ko_);              \
      rahi[ss][1] = ld8(ha_hi + 16 * Hn + ko_);    \
      ralo[ss][0] = ld8(ha_lo + ko_);              \
      ralo[ss][1] = ld8(ha_lo + 16 * Hn + ko_);    \
      rblo[ss][0] = ld8(wl + 0 * 16384 + ko_);     \
      rblo[ss][1] = ld8(wl + 1 * 16384 + ko_);     \
      rblo[ss][2] = ld8(wl + 2 * 16384 + ko_);     \
      rblo[ss][3] = ld8(wl + 3 * 16384 + ko_);     }

    LOADIT(0, 0);
    LOADIT(1, 1);
    #pragma unroll
    for (int c = 0; c < 16; ++c){
      const int slot = c % 3;
      if (c < 14) LOADIT(c + 2, (c + 2) % 3);
      const int c64o = (kg * 8 + (c >> 1)) * 4096;
      const int sslot = (((c & 1) * 4 + q) ^ (r & 7)) * 8;
      bf16x8 bhi[4];
      #pragma unroll
      for (int nt = 0; nt < 4; ++nt)
        bhi[nt] = ld8(&ldsW[c64o + (nt * 16 + r) * 64 + sslot]);
      #pragma unroll
      for (int mt = 0; mt < 2; ++mt)
        #pragma unroll
        for (int nt = 0; nt < 4; ++nt){
          acc[mt][nt] = __builtin_amdgcn_mfma_f32_16x16x32_bf16(rahi[slot][mt], bhi[nt], acc[mt][nt], 0, 0, 0);
          acc[mt][nt] = __builtin_amdgcn_mfma_f32_16x16x32_bf16(rahi[slot][mt], rblo[slot][nt], acc[mt][nt], 0, 0, 0);
          acc[mt][nt] = __builtin_amdgcn_mfma_f32_16x16x32_bf16(ralo[slot][mt], bhi[nt], acc[mt][nt], 0, 0, 0);
        }
    }
    #undef LOADIT

    // ---- k-half partial-sum exchange through LDS (two phases, 16 KB buffer) ----
    __syncthreads();
    if (kg == 1){
      #pragma unroll
      for (int nt = 0; nt < 4; ++nt)
        #pragma unroll
        for (int e = 0; e < 4; ++e)
          exch[((bgroup * 4 + nt) * 4 + e) * 64 + lane] = acc[0][nt][e];
    }
    __syncthreads();
    if (kg == 0){
      #pragma unroll
      for (int nt = 0; nt < 4; ++nt)
        #pragma unroll
        for (int e = 0; e < 4; ++e)
          acc[0][nt][e] += exch[((bgroup * 4 + nt) * 4 + e) * 64 + lane];
    }
    __syncthreads();
    if (kg == 1){
      #pragma unroll
      for (int nt = 0; nt < 4; ++nt)
        #pragma unroll
        for (int e = 0; e < 4; ++e)
          exch[((bgroup * 4 + nt) * 4 + e) * 64 + lane] = acc[1][nt][e];
    }
    __syncthreads();
    if (kg == 0){
      #pragma unroll
      for (int nt = 0; nt < 4; ++nt)
        #pragma unroll
        for (int e = 0; e < 4; ++e)
          acc[1][nt][e] += exch[((bgroup * 4 + nt) * 4 + e) * 64 + lane];
    }

    // ---- pointwise LSTM cell (kg0 waves; all 4 gates lane-local) ----
    if (kg == 0){
      float pp[8];
      #pragma unroll
      for (int mt = 0; mt < 2; ++mt)
        #pragma unroll
        for (int e = 0; e < 4; ++e){
          const int idx = mt * 4 + e;
          float gi = sigm(acc[mt][0][e]);
          float gf = sigm(acc[mt][1][e]);
          float gg = tanh_f(acc[mt][2][e]);
          float go = sigm(acc[mt][3][e]);
          float cn = gf * creg[idx] + gi * gg;
          creg[idx] = cn;
          float hn = go * tanh_f(cn);
          const int row = bt * 128 + bgroup * 32 + mt * 16 + q * 4 + e;
          u16 hi = f2bf(hn);
          hd_hi[row * Hn + j] = hi;
          hd_lo[row * Hn + j] = f2bf(hn - bf2f(hi));
          pp[idx] = hn * wout_r;
        }
      #pragma unroll
      for (int m = 1; m < 16; m <<= 1)
        #pragma unroll
        for (int idx = 0; idx < 8; ++idx)
          pp[idx] += __shfl_xor(pp[idx], m, 64);
      if (r == 0){
        #pragma unroll
        for (int mt = 0; mt < 2; ++mt)
          #pragma unroll
          for (int e = 0; e < 4; ++e){
            const int rowl = bgroup * 32 + mt * 16 + q * 4 + e;
            ypart[(pb * 4 + bt) * 8192 + rowl * 64 + jt] = pp[mt * 4 + e];
          }
      }
    }

    // ---- group barrier ----
    __builtin_amdgcn_fence(__ATOMIC_RELEASE, "agent");
    __syncthreads();
    if (tid == 0){
      __hip_atomic_fetch_add(cnt + bt, 1u, __ATOMIC_RELAXED, __HIP_MEMORY_SCOPE_AGENT);
      const u32 tgt = 64u * (u32)(t + 2);
      for (int spin = 0; spin < (1 << 18); ++spin){
        if (__hip_atomic_load(cnt + bt, __ATOMIC_RELAXED, __HIP_MEMORY_SCOPE_AGENT) >= tgt) break;
        __builtin_amdgcn_s_sleep(2);
      }
    }
    __syncthreads();
    __builtin_amdgcn_fence(__ATOMIC_ACQUIRE, "agent");

    // ---- x phase: y[b] = b_out + sum over 64 jt (coalesced, transposed ypart) ----
    {
      const int row = tid >> 2, quarter = tid & 3;
      const float* yp = ypart + (pb * 4 + bt) * 8192 + row * 64 + quarter * 16;
      float s = 0.f;
      #pragma unroll
      for (int j2 = 0; j2 < 16; ++j2) s += yp[j2];
      s += __shfl_xor(s, 1, 64);
      s += __shfl_xor(s, 2, 64);
      if (quarter == 0){
        const float y = bo + s;
        x_lds[row] = y;
        if (jt == 0) outp[(bt * 128 + row) * T + t] = y;
      }
    }
    __syncthreads();
  }
}

extern "C" void kernel_launch(void* const* d_in, const int* in_sizes, int n_in,
                              void* d_out, int out_size, void* d_ws, size_t ws_size,
                              hipStream_t stream)
{
  const float* z    = (const float*)d_in[0];
  const float* Wzh  = (const float*)d_in[1];
  const float* bzh  = (const float*)d_in[2];
  const float* Wzc  = (const float*)d_in[3];
  const float* bzc  = (const float*)d_in[4];
  const float* Wih  = (const float*)d_in[5];
  const float* Whh  = (const float*)d_in[6];
  const float* b_ih = (const float*)d_in[7];
  const float* b_hh = (const float*)d_in[8];
  const float* Wout = (const float*)d_in[9];
  const float* bout = (const float*)d_in[10];
  const int*   tlen = (const int*)d_in[11];
  float* outp = (float*)d_out;

  char* ws = (char*)d_ws;
  size_t off = 0;
  auto alloc = [&](size_t bytes) -> char* {
    char* p = ws + off;
    off += (bytes + 255) & ~size_t(255);
    return p;
  };
  u16* wp_hi  = (u16*)alloc((size_t)G4H * Hn * 2);
  u16* wp_lo  = (u16*)alloc((size_t)G4H * Hn * 2);
  u16* hb_hi  = (u16*)alloc((size_t)2 * Bsz * Hn * 2);
  u16* hb_lo  = (u16*)alloc((size_t)2 * Bsz * Hn * 2);
  u16* zp_hi  = (u16*)alloc((size_t)Bsz * LATn * 2);
  u16* zp_lo  = (u16*)alloc((size_t)Bsz * LATn * 2);
  u16* wzh_hi = (u16*)alloc((size_t)Hn * LATn * 2);
  u16* wzh_lo = (u16*)alloc((size_t)Hn * LATn * 2);
  u16* wzc_hi = (u16*)alloc((size_t)Hn * LATn * 2);
  u16* wzc_lo = (u16*)alloc((size_t)Hn * LATn * 2);
  float* bpack   = (float*)alloc((size_t)G4H * 4);
  float* wihpack = (float*)alloc((size_t)G4H * 4);
  float* ypart   = (float*)alloc((size_t)2 * 4 * 128 * 64 * 4);
  u32* cnt       = (u32*)alloc(256);

  repack_kernel<<<dim3(1024), dim3(256), 0, stream>>>(
      Whh, b_ih, b_hh, Wih, z, Wzh, Wzc,
      wp_hi, wp_lo, zp_hi, zp_lo, wzh_hi, wzh_lo, wzc_hi, wzc_lo,
      bpack, wihpack, cnt);

  lstm_persist<<<dim3(NBLK), dim3(512), 0, stream>>>(
      wp_hi, wp_lo, bpack, wihpack, Wout, bout,
      zp_hi, zp_lo, wzh_hi, wzh_lo, wzc_hi, wzc_lo,
      bzh, bzc, hb_hi, hb_lo, ypart, outp, tlen, cnt);
}